// Round 1
// baseline (1241.211 us; speedup 1.0000x reference)
//
#include <hip/hip_runtime.h>
#include <cstddef>

#define N_NODES 100000
#define N_EDGES 640000
#define D 128
#define LDSP 132   // LDS row pitch: 16B-aligned b128 reads, only 4-way broadcast-group conflict

// ---------------------------------------------------------------------------
// Scatter: summed[dst] += x[src]; deg[dst] += 1.
// One thread per (edge, 4-dim chunk): 640000 * 32 threads.
// ---------------------------------------------------------------------------
__global__ __launch_bounds__(256) void sage_scatter_kernel(
    const float* __restrict__ x,
    const int* __restrict__ edge_src,
    const int* __restrict__ edge_dst,
    float* __restrict__ summed,
    float* __restrict__ deg)
{
    int gid = blockIdx.x * 256 + threadIdx.x;
    int e = gid >> 5;
    int c = gid & 31;
    if (e >= N_EDGES) return;
    int src = edge_src[e];
    int dst = edge_dst[e];
    float4 v = *reinterpret_cast<const float4*>(x + (size_t)src * D + c * 4);
    float* p = summed + (size_t)dst * D + c * 4;
    atomicAdd(p + 0, v.x);
    atomicAdd(p + 1, v.y);
    atomicAdd(p + 2, v.z);
    atomicAdd(p + 3, v.w);
    if (c == 0) atomicAdd(deg + dst, 1.0f);
}

// ---------------------------------------------------------------------------
// Fused: out = (summed/max(deg,1)) @ weight + x @ root_weight + bias
// Block = 256 threads, tile = 32 nodes x 128 cols.
// Thread (ty,tx) computes 4 nodes x 4 cols via register outer-product.
// ---------------------------------------------------------------------------
__global__ __launch_bounds__(256) void sage_gemm_kernel(
    const float* __restrict__ x,
    const float* __restrict__ weight,
    const float* __restrict__ root_weight,
    const float* __restrict__ bias,
    const float* __restrict__ summed,
    const float* __restrict__ deg,
    float* __restrict__ out)
{
    __shared__ float a_mean[32][LDSP];
    __shared__ float a_x[32][LDSP];
    __shared__ float s_inv[32];

    const int t = threadIdx.x;
    const int base = blockIdx.x * 32;

    if (t < 32) {
        s_inv[t] = 1.0f / fmaxf(deg[base + t], 1.0f);
    }
    __syncthreads();

    // Stage 32 rows x 128 cols of mean (summed * invdeg) and x into LDS.
    // 32*32 float4 elements, 256 threads -> 4 each; fully coalesced.
    for (int i = t; i < 32 * 32; i += 256) {
        int row = i >> 5;
        int c4 = i & 31;
        const float inv = s_inv[row];
        float4 vs = *reinterpret_cast<const float4*>(summed + (size_t)(base + row) * D + c4 * 4);
        vs.x *= inv; vs.y *= inv; vs.z *= inv; vs.w *= inv;
        *reinterpret_cast<float4*>(&a_mean[row][c4 * 4]) = vs;
        float4 vx = *reinterpret_cast<const float4*>(x + (size_t)(base + row) * D + c4 * 4);
        *reinterpret_cast<float4*>(&a_x[row][c4 * 4]) = vx;
    }
    __syncthreads();

    const int tx = t & 31;   // column group: cols j0..j0+3
    const int ty = t >> 5;   // node group:  rows m0..m0+3
    const int j0 = tx * 4;
    const int m0 = ty * 4;

    const float4 b4 = *reinterpret_cast<const float4*>(bias + j0);
    float acc[4][4];
#pragma unroll
    for (int m = 0; m < 4; ++m) {
        acc[m][0] = b4.x; acc[m][1] = b4.y; acc[m][2] = b4.z; acc[m][3] = b4.w;
    }

    // mean @ weight
    for (int k = 0; k < D; k += 4) {
        float4 w0 = *reinterpret_cast<const float4*>(weight + (size_t)(k + 0) * D + j0);
        float4 w1 = *reinterpret_cast<const float4*>(weight + (size_t)(k + 1) * D + j0);
        float4 w2 = *reinterpret_cast<const float4*>(weight + (size_t)(k + 2) * D + j0);
        float4 w3 = *reinterpret_cast<const float4*>(weight + (size_t)(k + 3) * D + j0);
#pragma unroll
        for (int m = 0; m < 4; ++m) {
            float4 a = *reinterpret_cast<const float4*>(&a_mean[m0 + m][k]);
            acc[m][0] += a.x * w0.x + a.y * w1.x + a.z * w2.x + a.w * w3.x;
            acc[m][1] += a.x * w0.y + a.y * w1.y + a.z * w2.y + a.w * w3.y;
            acc[m][2] += a.x * w0.z + a.y * w1.z + a.z * w2.z + a.w * w3.z;
            acc[m][3] += a.x * w0.w + a.y * w1.w + a.z * w2.w + a.w * w3.w;
        }
    }

    // x @ root_weight
    for (int k = 0; k < D; k += 4) {
        float4 w0 = *reinterpret_cast<const float4*>(root_weight + (size_t)(k + 0) * D + j0);
        float4 w1 = *reinterpret_cast<const float4*>(root_weight + (size_t)(k + 1) * D + j0);
        float4 w2 = *reinterpret_cast<const float4*>(root_weight + (size_t)(k + 2) * D + j0);
        float4 w3 = *reinterpret_cast<const float4*>(root_weight + (size_t)(k + 3) * D + j0);
#pragma unroll
        for (int m = 0; m < 4; ++m) {
            float4 a = *reinterpret_cast<const float4*>(&a_x[m0 + m][k]);
            acc[m][0] += a.x * w0.x + a.y * w1.x + a.z * w2.x + a.w * w3.x;
            acc[m][1] += a.x * w0.y + a.y * w1.y + a.z * w2.y + a.w * w3.y;
            acc[m][2] += a.x * w0.z + a.y * w1.z + a.z * w2.z + a.w * w3.z;
            acc[m][3] += a.x * w0.w + a.y * w1.w + a.z * w2.w + a.w * w3.w;
        }
    }

#pragma unroll
    for (int m = 0; m < 4; ++m) {
        *reinterpret_cast<float4*>(out + (size_t)(base + m0 + m) * D + j0) =
            make_float4(acc[m][0], acc[m][1], acc[m][2], acc[m][3]);
    }
}

extern "C" void kernel_launch(void* const* d_in, const int* in_sizes, int n_in,
                              void* d_out, int out_size, void* d_ws, size_t ws_size,
                              hipStream_t stream) {
    const float* x           = (const float*)d_in[0];
    const float* weight      = (const float*)d_in[1];
    const float* root_weight = (const float*)d_in[2];
    const float* bias        = (const float*)d_in[3];
    const int* edge_src      = (const int*)d_in[4];
    const int* edge_dst      = (const int*)d_in[5];
    float* out = (float*)d_out;

    float* summed = (float*)d_ws;                         // [N_NODES * D]
    float* deg    = summed + (size_t)N_NODES * D;         // [N_NODES]

    size_t zero_bytes = ((size_t)N_NODES * D + N_NODES) * sizeof(float);
    hipMemsetAsync(d_ws, 0, zero_bytes, stream);

    const int scatter_blocks = (N_EDGES * 32) / 256;      // 80000
    sage_scatter_kernel<<<scatter_blocks, 256, 0, stream>>>(x, edge_src, edge_dst, summed, deg);

    sage_gemm_kernel<<<N_NODES / 32, 256, 0, stream>>>(   // 3125 blocks
        x, weight, root_weight, bias, summed, deg, out);
}

// Round 2
// 452.169 us; speedup vs baseline: 2.7450x; 2.7450x over previous
//
#include <hip/hip_runtime.h>
#include <cstddef>

#define N_NODES 100000
#define N_EDGES 640000
#define D 128
#define LDSP 132   // LDS row pitch: keeps float4 reads 16B-aligned, broadcast-friendly

// ---------------------------------------------------------------------------
// 1) Count in-degree with int atomics.
// ---------------------------------------------------------------------------
__global__ __launch_bounds__(256) void deg_count_kernel(
    const int* __restrict__ edge_dst, int* __restrict__ deg_i)
{
    int e = blockIdx.x * 256 + threadIdx.x;
    if (e >= N_EDGES) return;
    atomicAdd(&deg_i[edge_dst[e]], 1);
}

// ---------------------------------------------------------------------------
// 2) Exclusive scan of deg_i -> row_start (single block, 1024 threads).
//    Each thread sequentially owns a 98-element chunk; Hillis-Steele over
//    the 1024 chunk sums in LDS; rescan chunks with offset.
// ---------------------------------------------------------------------------
__global__ __launch_bounds__(1024) void scan_kernel(
    const int* __restrict__ deg_i, int* __restrict__ row_start)
{
    __shared__ int sums[1024];
    const int t = threadIdx.x;
    const int CH = (N_NODES + 1023) / 1024;       // 98
    int begin = t * CH;
    int end = begin + CH; if (end > N_NODES) end = N_NODES;
    if (begin > N_NODES) begin = N_NODES;

    int s = 0;
    for (int i = begin; i < end; ++i) s += deg_i[i];
    sums[t] = s;
    __syncthreads();

    for (int off = 1; off < 1024; off <<= 1) {
        int v = (t >= off) ? sums[t - off] : 0;
        __syncthreads();
        sums[t] += v;
        __syncthreads();
    }

    int excl = (t == 0) ? 0 : sums[t - 1];
    for (int i = begin; i < end; ++i) {
        int d = deg_i[i];
        row_start[i] = excl;
        excl += d;
    }
    if (t == 1023) row_start[N_NODES] = excl;     // == N_EDGES
}

// ---------------------------------------------------------------------------
// 3) Fill CSR: csr_src[row_start[dst] + cursor[dst]++] = src.
// ---------------------------------------------------------------------------
__global__ __launch_bounds__(256) void csr_fill_kernel(
    const int* __restrict__ edge_src, const int* __restrict__ edge_dst,
    const int* __restrict__ row_start, int* __restrict__ cursor,
    int* __restrict__ csr_src)
{
    int e = blockIdx.x * 256 + threadIdx.x;
    if (e >= N_EDGES) return;
    int dst = edge_dst[e];
    int pos = row_start[dst] + atomicAdd(&cursor[dst], 1);
    csr_src[pos] = edge_src[e];
}

// ---------------------------------------------------------------------------
// 4) Fused: gather-mean into LDS, then
//    out = mean @ weight + x @ root_weight + bias
//    Block = 256 threads (4 waves), tile = 32 nodes x 128 cols.
// ---------------------------------------------------------------------------
__global__ __launch_bounds__(256) void sage_fused_gemm_kernel(
    const float* __restrict__ x,
    const float* __restrict__ weight,
    const float* __restrict__ root_weight,
    const float* __restrict__ bias,
    const int* __restrict__ row_start,
    const int* __restrict__ csr_src,
    float* __restrict__ out)
{
    __shared__ float a_mean[32][LDSP];
    __shared__ float a_x[32][LDSP];

    const int t = threadIdx.x;
    const int base = blockIdx.x * 32;

    // Stage x tile (coalesced): 32 rows x 32 float4, 256 threads -> 4 each.
    for (int i = t; i < 32 * 32; i += 256) {
        int row = i >> 5;
        int c4 = i & 31;
        float4 vx = *reinterpret_cast<const float4*>(x + (size_t)(base + row) * D + c4 * 4);
        *reinterpret_cast<float4*>(&a_x[row][c4 * 4]) = vx;
    }

    // Gather-mean: wave w handles nodes w*8 .. w*8+7; lane owns dims 2l,2l+1.
    const int wave = t >> 6;
    const int lane = t & 63;
    for (int n = wave * 8; n < wave * 8 + 8; ++n) {
        const int node = base + n;
        const int rs = row_start[node];
        const int re = row_start[node + 1];
        float ax = 0.0f, ay = 0.0f;
        for (int e = rs; e < re; ++e) {
            const int s = csr_src[e];     // wave-uniform -> scalar load
            float2 v = *reinterpret_cast<const float2*>(x + (size_t)s * D + lane * 2);
            ax += v.x; ay += v.y;
        }
        const float inv = 1.0f / fmaxf((float)(re - rs), 1.0f);
        float2 r; r.x = ax * inv; r.y = ay * inv;
        *reinterpret_cast<float2*>(&a_mean[n][lane * 2]) = r;
    }
    __syncthreads();

    const int tx = t & 31;   // column group: cols j0..j0+3
    const int ty = t >> 5;   // node group:  rows m0..m0+3
    const int j0 = tx * 4;
    const int m0 = ty * 4;

    const float4 b4 = *reinterpret_cast<const float4*>(bias + j0);
    float acc[4][4];
#pragma unroll
    for (int m = 0; m < 4; ++m) {
        acc[m][0] = b4.x; acc[m][1] = b4.y; acc[m][2] = b4.z; acc[m][3] = b4.w;
    }

    // mean @ weight
    for (int k = 0; k < D; k += 4) {
        float4 w0 = *reinterpret_cast<const float4*>(weight + (size_t)(k + 0) * D + j0);
        float4 w1 = *reinterpret_cast<const float4*>(weight + (size_t)(k + 1) * D + j0);
        float4 w2 = *reinterpret_cast<const float4*>(weight + (size_t)(k + 2) * D + j0);
        float4 w3 = *reinterpret_cast<const float4*>(weight + (size_t)(k + 3) * D + j0);
#pragma unroll
        for (int m = 0; m < 4; ++m) {
            float4 a = *reinterpret_cast<const float4*>(&a_mean[m0 + m][k]);
            acc[m][0] += a.x * w0.x + a.y * w1.x + a.z * w2.x + a.w * w3.x;
            acc[m][1] += a.x * w0.y + a.y * w1.y + a.z * w2.y + a.w * w3.y;
            acc[m][2] += a.x * w0.z + a.y * w1.z + a.z * w2.z + a.w * w3.z;
            acc[m][3] += a.x * w0.w + a.y * w1.w + a.z * w2.w + a.w * w3.w;
        }
    }

    // x @ root_weight
    for (int k = 0; k < D; k += 4) {
        float4 w0 = *reinterpret_cast<const float4*>(root_weight + (size_t)(k + 0) * D + j0);
        float4 w1 = *reinterpret_cast<const float4*>(root_weight + (size_t)(k + 1) * D + j0);
        float4 w2 = *reinterpret_cast<const float4*>(root_weight + (size_t)(k + 2) * D + j0);
        float4 w3 = *reinterpret_cast<const float4*>(root_weight + (size_t)(k + 3) * D + j0);
#pragma unroll
        for (int m = 0; m < 4; ++m) {
            float4 a = *reinterpret_cast<const float4*>(&a_x[m0 + m][k]);
            acc[m][0] += a.x * w0.x + a.y * w1.x + a.z * w2.x + a.w * w3.x;
            acc[m][1] += a.x * w0.y + a.y * w1.y + a.z * w2.y + a.w * w3.y;
            acc[m][2] += a.x * w0.z + a.y * w1.z + a.z * w2.z + a.w * w3.z;
            acc[m][3] += a.x * w0.w + a.y * w1.w + a.z * w2.w + a.w * w3.w;
        }
    }

#pragma unroll
    for (int m = 0; m < 4; ++m) {
        *reinterpret_cast<float4*>(out + (size_t)(base + m0 + m) * D + j0) =
            make_float4(acc[m][0], acc[m][1], acc[m][2], acc[m][3]);
    }
}

extern "C" void kernel_launch(void* const* d_in, const int* in_sizes, int n_in,
                              void* d_out, int out_size, void* d_ws, size_t ws_size,
                              hipStream_t stream) {
    const float* x           = (const float*)d_in[0];
    const float* weight      = (const float*)d_in[1];
    const float* root_weight = (const float*)d_in[2];
    const float* bias        = (const float*)d_in[3];
    const int* edge_src      = (const int*)d_in[4];
    const int* edge_dst      = (const int*)d_in[5];
    float* out = (float*)d_out;

    // ws layout (ints): deg_i[N] | cursor[N] | row_start[N+1] | csr_src[E]
    int* deg_i     = (int*)d_ws;
    int* cursor    = deg_i + N_NODES;
    int* row_start = cursor + N_NODES;
    int* csr_src   = row_start + (N_NODES + 1);

    // Zero deg_i and cursor (contiguous).
    hipMemsetAsync(deg_i, 0, 2 * (size_t)N_NODES * sizeof(int), stream);

    const int eb = (N_EDGES + 255) / 256;   // 2500
    deg_count_kernel<<<eb, 256, 0, stream>>>(edge_dst, deg_i);
    scan_kernel<<<1, 1024, 0, stream>>>(deg_i, row_start);
    csr_fill_kernel<<<eb, 256, 0, stream>>>(edge_src, edge_dst, row_start, cursor, csr_src);
    sage_fused_gemm_kernel<<<N_NODES / 32, 256, 0, stream>>>(
        x, weight, root_weight, bias, row_start, csr_src, out);
}